// Round 1
// baseline (488.984 us; speedup 1.0000x reference)
//
#include <hip/hip_runtime.h>

#define N_NODES 100000
#define N_EDGES 1600000
#define DIM 128
#define BN_EPS 1e-5f

// ---------------- degree count ----------------
__global__ void k_deg(const int* __restrict__ col, int* __restrict__ deg, int E) {
    int e = blockIdx.x * 256 + threadIdx.x;
    if (e < E) atomicAdd(&deg[col[e]], 1);
}

// ---------------- dinv = rsqrt(deg + 1 self loop) ----------------
__global__ void k_dinv(const int* __restrict__ deg, float* __restrict__ dinv, int n) {
    int i = blockIdx.x * 256 + threadIdx.x;
    if (i < n) dinv[i] = rsqrtf((float)(deg[i] + 1));
}

// ---------------- scan part 1: per-block sums ----------------
__global__ void k_part(const int* __restrict__ deg, int* __restrict__ parts, int n) {
    __shared__ int sd[256];
    int tid = threadIdx.x;
    int idx = blockIdx.x * 256 + tid;
    sd[tid] = (idx < n) ? deg[idx] : 0;
    __syncthreads();
    for (int o = 128; o > 0; o >>= 1) {
        if (tid < o) sd[tid] += sd[tid + o];
        __syncthreads();
    }
    if (tid == 0) parts[blockIdx.x] = sd[0];
}

// ---------------- scan part 2: scan the partials (1 block) ----------------
__global__ void k_top(const int* __restrict__ parts, int* __restrict__ pscan, int np) {
    __shared__ int sd[256];
    __shared__ int run_s;
    int tid = threadIdx.x;
    if (tid == 0) run_s = 0;
    __syncthreads();
    for (int base = 0; base < np; base += 256) {
        int idx = base + tid;
        int v = (idx < np) ? parts[idx] : 0;
        sd[tid] = v;
        __syncthreads();
        for (int o = 1; o < 256; o <<= 1) {
            int t = (tid >= o) ? sd[tid - o] : 0;
            __syncthreads();
            sd[tid] += t;
            __syncthreads();
        }
        int brun = run_s;
        if (idx < np) pscan[idx] = brun + sd[tid] - v;  // exclusive
        __syncthreads();
        if (tid == 0) run_s += sd[255];
        __syncthreads();
    }
}

// ---------------- scan part 3: per-element exclusive offsets ----------------
__global__ void k_apply(const int* __restrict__ deg, const int* __restrict__ pscan,
                        int* __restrict__ offs, int* __restrict__ cursor, int n) {
    __shared__ int sd[256];
    int tid = threadIdx.x;
    int idx = blockIdx.x * 256 + tid;
    int v = (idx < n) ? deg[idx] : 0;
    sd[tid] = v;
    __syncthreads();
    for (int o = 1; o < 256; o <<= 1) {
        int t = (tid >= o) ? sd[tid - o] : 0;
        __syncthreads();
        sd[tid] += t;
        __syncthreads();
    }
    if (idx < n) {
        int ex = pscan[blockIdx.x] + sd[tid] - v;
        offs[idx] = ex;
        cursor[idx] = ex;
    }
}

// ---------------- scatter edges into CSR buckets ----------------
__global__ void k_scatter(const int* __restrict__ ei, int* __restrict__ cursor,
                          int* __restrict__ csr, int E) {
    int e = blockIdx.x * 256 + threadIdx.x;
    if (e < E) {
        int src = ei[e];
        int dst = ei[E + e];
        int pos = atomicAdd(&cursor[dst], 1);
        csr[pos] = src;
    }
}

// ---------------- GEMM h = x @ W^T  (f32, LDS-tiled, 4x4 microtile) ----------------
// block: 512 threads = 32 col-groups x 16 row-groups; 64 rows x 128 cols per block
// K split in 2 halves of 64 to keep LDS <= 64KB static.
#define WT_S 132
#define XS_S 68
__global__ __launch_bounds__(512) void k_gemm(const float* __restrict__ x,
                                              const float* __restrict__ W,
                                              float* __restrict__ h, int n) {
    __shared__ float WT[64 * WT_S];   // WT[k][c] = W[c][kh*64+k]   33792 B
    __shared__ float XS[64 * XS_S];   // XS[k][r] = x[rbase+r][kh*64+k] 17408 B
    int t = threadIdx.x;
    int cg = t & 31;    // col group: cols 4cg..4cg+3
    int rg = t >> 5;    // row group: rows 4rg..4rg+3 (0..15)
    int c0 = cg * 4, r0 = rg * 4;
    int rbase = blockIdx.x * 64;
    float acc[4][4] = {};

    for (int kh = 0; kh < 2; kh++) {
        int kbase = kh * 64;
        // stage W half: 128 cols x 64 k = 8192 words
        for (int idx = t; idx < 128 * 64; idx += 512) {
            int c = idx >> 6, k = idx & 63;
            WT[k * WT_S + c] = W[c * 128 + kbase + k];
        }
        // stage x half: 64 rows x 64 k
        for (int idx = t; idx < 64 * 64; idx += 512) {
            int r = idx >> 6, k = idx & 63;
            int gr = rbase + r;
            XS[k * XS_S + r] = (gr < n) ? x[gr * 128 + kbase + k] : 0.0f;
        }
        __syncthreads();
        #pragma unroll
        for (int k = 0; k < 64; k += 4) {
            #pragma unroll
            for (int kk = 0; kk < 4; kk++) {
                float4 xv = *(const float4*)&XS[(k + kk) * XS_S + r0];
                float4 wv = *(const float4*)&WT[(k + kk) * WT_S + c0];
                acc[0][0] += xv.x * wv.x; acc[0][1] += xv.x * wv.y;
                acc[0][2] += xv.x * wv.z; acc[0][3] += xv.x * wv.w;
                acc[1][0] += xv.y * wv.x; acc[1][1] += xv.y * wv.y;
                acc[1][2] += xv.y * wv.z; acc[1][3] += xv.y * wv.w;
                acc[2][0] += xv.z * wv.x; acc[2][1] += xv.z * wv.y;
                acc[2][2] += xv.z * wv.z; acc[2][3] += xv.z * wv.w;
                acc[3][0] += xv.w * wv.x; acc[3][1] += xv.w * wv.y;
                acc[3][2] += xv.w * wv.z; acc[3][3] += xv.w * wv.w;
            }
        }
        __syncthreads();
    }
    #pragma unroll
    for (int i = 0; i < 4; i++) {
        int gr = rbase + r0 + i;
        if (gr < n) {
            float4 st = make_float4(acc[i][0], acc[i][1], acc[i][2], acc[i][3]);
            *(float4*)&h[gr * 128 + c0] = st;
        }
    }
}

// ---------------- aggregation: one wave per node ----------------
__global__ void k_agg(const float* __restrict__ h, const float* __restrict__ dinv,
                      const int* __restrict__ offs, const int* __restrict__ deg,
                      const int* __restrict__ csr, float* __restrict__ out, int n) {
    int w = threadIdx.x >> 6;
    int l = threadIdx.x & 63;
    int i = blockIdx.x * 4 + w;
    if (i >= n) return;
    const float2* hp = (const float2*)h;
    float di = dinv[i];
    float2 self = hp[i * 64 + l];
    float sn = di * di;
    float ax = self.x * sn, ay = self.y * sn;
    int s0 = offs[i];
    int cnt = deg[i];
    for (int e = 0; e < cnt; e++) {
        int src = csr[s0 + e];
        float nrm = di * dinv[src];
        float2 hv = hp[src * 64 + l];
        ax += nrm * hv.x;
        ay += nrm * hv.y;
    }
    ((float2*)out)[i * 64 + l] = make_float2(ax, ay);
}

// ---------------- BN stats: per-column sum & sumsq ----------------
__global__ void k_stats(const float* __restrict__ out, float* __restrict__ sums,
                        float* __restrict__ sumsq, int n) {
    int tid = threadIdx.x;
    int c = tid & 127;
    int rh = tid >> 7;  // 0..1
    float s = 0.f, s2 = 0.f;
    for (int r = blockIdx.x * 2 + rh; r < n; r += gridDim.x * 2) {
        float v = out[r * 128 + c];
        s += v;
        s2 += v * v;
    }
    __shared__ float ls[256], ls2[256];
    ls[tid] = s; ls2[tid] = s2;
    __syncthreads();
    if (tid < 128) {
        s = ls[tid] + ls[tid + 128];
        s2 = ls2[tid] + ls2[tid + 128];
        atomicAdd(&sums[c], s);
        atomicAdd(&sumsq[c], s2);
    }
}

// ---------------- BN normalize + ReLU (in place on out) ----------------
__global__ void k_bn(float* __restrict__ out, const float* __restrict__ sums,
                     const float* __restrict__ sumsq, const float* __restrict__ gamma,
                     const float* __restrict__ beta, int n) {
    int idx = blockIdx.x * 256 + threadIdx.x;       // float4 index
    int total = n * 32;                              // n*128/4
    if (idx >= total) return;
    int c0 = (idx & 31) * 4;
    float invN = 1.0f / (float)n;
    float4 v = ((const float4*)out)[idx];
    float r[4] = {v.x, v.y, v.z, v.w};
    #pragma unroll
    for (int j = 0; j < 4; j++) {
        int c = c0 + j;
        float mean = sums[c] * invN;
        float var = sumsq[c] * invN - mean * mean;
        float scale = rsqrtf(var + BN_EPS) * gamma[c];
        float o = (r[j] - mean) * scale + beta[c];
        r[j] = fmaxf(o, 0.0f);
    }
    ((float4*)out)[idx] = make_float4(r[0], r[1], r[2], r[3]);
}

extern "C" void kernel_launch(void* const* d_in, const int* in_sizes, int n_in,
                              void* d_out, int out_size, void* d_ws, size_t ws_size,
                              hipStream_t stream) {
    const float* x     = (const float*)d_in[0];
    const int*   ei    = (const int*)d_in[1];     // [2][E]
    const float* W     = (const float*)d_in[2];
    // d_in[3] = b : cancels exactly under training-mode BatchNorm -> unused
    const float* gamma = (const float*)d_in[4];
    const float* beta  = (const float*)d_in[5];
    float* out = (float*)d_out;

    const int n = N_NODES, E = N_EDGES;

    // workspace layout
    float* h      = (float*)d_ws;                   // 12.8M floats
    float* dinv   = h + 12800000;                   // 100k
    int*   deg    = (int*)(dinv + 100000);          // 100k
    int*   offs   = deg + 100000;
    int*   cursor = offs + 100000;
    int*   csr    = cursor + 100000;                // 1.6M
    int*   parts  = csr + 1600000;                  // 512
    int*   pscan  = parts + 512;                    // 512
    float* sums   = (float*)(pscan + 512);          // 128
    float* sumsq  = sums + 128;                     // 128

    const int nb256 = (n + 255) / 256;              // 391

    hipMemsetAsync(deg, 0, n * sizeof(int), stream);
    hipMemsetAsync(sums, 0, 256 * sizeof(float), stream);

    k_deg<<<(E + 255) / 256, 256, 0, stream>>>(ei + E, deg, E);
    k_dinv<<<nb256, 256, 0, stream>>>(deg, dinv, n);
    k_part<<<nb256, 256, 0, stream>>>(deg, parts, n);
    k_top<<<1, 256, 0, stream>>>(parts, pscan, nb256);
    k_apply<<<nb256, 256, 0, stream>>>(deg, pscan, offs, cursor, n);
    k_scatter<<<(E + 255) / 256, 256, 0, stream>>>(ei, cursor, csr, E);

    k_gemm<<<(n + 63) / 64, 512, 0, stream>>>(x, W, h, n);

    k_agg<<<(n + 3) / 4, 256, 0, stream>>>(h, dinv, offs, deg, csr, out, n);

    k_stats<<<512, 256, 0, stream>>>(out, sums, sumsq, n);
    k_bn<<<(n * 32 + 255) / 256, 256, 0, stream>>>(out, sums, sumsq, gamma, beta, n);
}

// Round 2
// 397.221 us; speedup vs baseline: 1.2310x; 1.2310x over previous
//
#include <hip/hip_runtime.h>

#define N_NODES 100000
#define N_EDGES 1600000
#define DIM 128
#define BN_EPS 1e-5f

typedef short short8 __attribute__((ext_vector_type(8)));
typedef float floatx4 __attribute__((ext_vector_type(4)));

__device__ __forceinline__ unsigned short f2bf(float f) {
    unsigned int u = __float_as_uint(f);
    unsigned int r = (u + 0x7fffu + ((u >> 16) & 1u)) >> 16;  // RNE
    return (unsigned short)r;
}

// ---------------- degree count ----------------
__global__ void k_deg(const int* __restrict__ col, int* __restrict__ deg, int E) {
    int e = blockIdx.x * 256 + threadIdx.x;
    if (e < E) atomicAdd(&deg[col[e]], 1);
}

// ---------------- dinv = rsqrt(deg + 1 self loop) ----------------
__global__ void k_dinv(const int* __restrict__ deg, float* __restrict__ dinv, int n) {
    int i = blockIdx.x * 256 + threadIdx.x;
    if (i < n) dinv[i] = rsqrtf((float)(deg[i] + 1));
}

// ---------------- scan part 1: per-block sums ----------------
__global__ void k_part(const int* __restrict__ deg, int* __restrict__ parts, int n) {
    __shared__ int sd[256];
    int tid = threadIdx.x;
    int idx = blockIdx.x * 256 + tid;
    sd[tid] = (idx < n) ? deg[idx] : 0;
    __syncthreads();
    for (int o = 128; o > 0; o >>= 1) {
        if (tid < o) sd[tid] += sd[tid + o];
        __syncthreads();
    }
    if (tid == 0) parts[blockIdx.x] = sd[0];
}

// ---------------- scan part 2: scan the partials (1 block) ----------------
__global__ void k_top(const int* __restrict__ parts, int* __restrict__ pscan, int np) {
    __shared__ int sd[256];
    __shared__ int run_s;
    int tid = threadIdx.x;
    if (tid == 0) run_s = 0;
    __syncthreads();
    for (int base = 0; base < np; base += 256) {
        int idx = base + tid;
        int v = (idx < np) ? parts[idx] : 0;
        sd[tid] = v;
        __syncthreads();
        for (int o = 1; o < 256; o <<= 1) {
            int t = (tid >= o) ? sd[tid - o] : 0;
            __syncthreads();
            sd[tid] += t;
            __syncthreads();
        }
        int brun = run_s;
        if (idx < np) pscan[idx] = brun + sd[tid] - v;  // exclusive
        __syncthreads();
        if (tid == 0) run_s += sd[255];
        __syncthreads();
    }
}

// ---------------- scan part 3: per-element exclusive offsets ----------------
__global__ void k_apply(const int* __restrict__ deg, const int* __restrict__ pscan,
                        int* __restrict__ offs, int* __restrict__ cursor, int n) {
    __shared__ int sd[256];
    int tid = threadIdx.x;
    int idx = blockIdx.x * 256 + tid;
    int v = (idx < n) ? deg[idx] : 0;
    sd[tid] = v;
    __syncthreads();
    for (int o = 1; o < 256; o <<= 1) {
        int t = (tid >= o) ? sd[tid - o] : 0;
        __syncthreads();
        sd[tid] += t;
        __syncthreads();
    }
    if (idx < n) {
        int ex = pscan[blockIdx.x] + sd[tid] - v;
        offs[idx] = ex;
        cursor[idx] = ex;
    }
}

// ---------------- scatter edges into CSR buckets ----------------
__global__ void k_scatter(const int* __restrict__ ei, int* __restrict__ cursor,
                          int* __restrict__ csr, int E) {
    int e = blockIdx.x * 256 + threadIdx.x;
    if (e < E) {
        int src = ei[e];
        int dst = ei[E + e];
        int pos = atomicAdd(&cursor[dst], 1);
        csr[pos] = src;
    }
}

// ---------------- W f32 -> bf16 ----------------
__global__ void k_wcvt(const float* __restrict__ Wf, unsigned short* __restrict__ Wb) {
    int i = blockIdx.x * 256 + threadIdx.x;
    if (i < 128 * 128) Wb[i] = f2bf(Wf[i]);
}

// ---------------- GEMM h = x @ W^T via bf16 MFMA, h stored as bf16 ----------------
// 256 threads = 4 waves; each wave owns 64 rows (4 row-tiles of 16).
// No LDS, no barriers: A-frags from global f32 (converted), B-frags from pre-converted W_bf16 (L2-hot).
__global__ __launch_bounds__(256) void k_gemm(const float* __restrict__ x,
                                              const unsigned short* __restrict__ Wb,
                                              unsigned short* __restrict__ hb, int n) {
    int w = threadIdx.x >> 6;
    int l = threadIdx.x & 63;
    int rowbase = blockIdx.x * 256 + w * 64;
    int r16 = l & 15;       // row-in-tile / col-in-tile
    int kg = l >> 4;        // k-subgroup 0..3

    // A fragments: a[m][q] covers rows rowbase+m*16.., k-chunk q*32
    short8 a[4][4];
    #pragma unroll
    for (int m = 0; m < 4; m++) {
        int row = rowbase + m * 16 + r16;
        int rca = min(row, n - 1);
        const float* base = x + rca * 128;
        #pragma unroll
        for (int q = 0; q < 4; q++) {
            const float4* xp = (const float4*)(base + q * 32 + kg * 8);
            float4 lo = xp[0], hi = xp[1];
            short8 af;
            af[0] = (short)f2bf(lo.x); af[1] = (short)f2bf(lo.y);
            af[2] = (short)f2bf(lo.z); af[3] = (short)f2bf(lo.w);
            af[4] = (short)f2bf(hi.x); af[5] = (short)f2bf(hi.y);
            af[6] = (short)f2bf(hi.z); af[7] = (short)f2bf(hi.w);
            a[m][q] = af;
        }
    }

    // loop over 8 N-tiles of 16 cols
    for (int t = 0; t < 8; t++) {
        int col = t * 16 + r16;
        short8 b[4];
        #pragma unroll
        for (int q = 0; q < 4; q++)
            b[q] = *(const short8*)(Wb + col * 128 + q * 32 + kg * 8);

        floatx4 acc[4] = {};
        #pragma unroll
        for (int m = 0; m < 4; m++)
            #pragma unroll
            for (int q = 0; q < 4; q++)
                acc[m] = __builtin_amdgcn_mfma_f32_16x16x32_bf16(a[m][q], b[q], acc[m], 0, 0, 0);

        #pragma unroll
        for (int m = 0; m < 4; m++) {
            #pragma unroll
            for (int r = 0; r < 4; r++) {
                int row = rowbase + m * 16 + kg * 4 + r;   // C/D: row=(lane>>4)*4+reg
                if (row < n) hb[row * 128 + col] = f2bf(acc[m][r]);
            }
        }
    }
}

// ---------------- aggregation: one wave per node, bf16 h gather ----------------
__global__ void k_agg(const unsigned int* __restrict__ hp, const float* __restrict__ dinv,
                      const int* __restrict__ offs, const int* __restrict__ deg,
                      const int* __restrict__ csr, float* __restrict__ out, int n) {
    int w = threadIdx.x >> 6;
    int l = threadIdx.x & 63;
    int i = blockIdx.x * 4 + w;
    if (i >= n) return;
    float di = dinv[i];
    unsigned int sv = hp[i * 64 + l];           // 2 bf16 = cols 2l, 2l+1
    float sn = di * di;
    float ax = __uint_as_float(sv << 16) * sn;
    float ay = __uint_as_float(sv & 0xffff0000u) * sn;
    int s0 = offs[i];
    int cnt = deg[i];
    for (int base = 0; base < cnt; base += 64) {
        int rem = min(cnt - base, 64);
        // lane-parallel prefetch of indices and their dinv
        int   myidx = (l < rem) ? csr[s0 + base + l] : 0;
        float mydi  = (l < rem) ? dinv[myidx] : 0.0f;
        for (int e = 0; e < rem; e++) {
            int src = __shfl(myidx, e);
            float nrm = di * __shfl(mydi, e);
            unsigned int hv = hp[src * 64 + l];
            ax += nrm * __uint_as_float(hv << 16);
            ay += nrm * __uint_as_float(hv & 0xffff0000u);
        }
    }
    ((float2*)out)[i * 64 + l] = make_float2(ax, ay);
}

// ---------------- BN stats: per-column sum & sumsq ----------------
__global__ void k_stats(const float* __restrict__ out, float* __restrict__ sums,
                        float* __restrict__ sumsq, int n) {
    int tid = threadIdx.x;
    int c = tid & 127;
    int rh = tid >> 7;  // 0..1
    float s = 0.f, s2 = 0.f;
    for (int r = blockIdx.x * 2 + rh; r < n; r += gridDim.x * 2) {
        float v = out[r * 128 + c];
        s += v;
        s2 += v * v;
    }
    __shared__ float ls[256], ls2[256];
    ls[tid] = s; ls2[tid] = s2;
    __syncthreads();
    if (tid < 128) {
        s = ls[tid] + ls[tid + 128];
        s2 = ls2[tid] + ls2[tid + 128];
        atomicAdd(&sums[c], s);
        atomicAdd(&sumsq[c], s2);
    }
}

// ---------------- BN normalize + ReLU (in place on out) ----------------
__global__ void k_bn(float* __restrict__ out, const float* __restrict__ sums,
                     const float* __restrict__ sumsq, const float* __restrict__ gamma,
                     const float* __restrict__ beta, int n) {
    int idx = blockIdx.x * 256 + threadIdx.x;       // float4 index
    int total = n * 32;                              // n*128/4
    if (idx >= total) return;
    int c0 = (idx & 31) * 4;
    float invN = 1.0f / (float)n;
    float4 v = ((const float4*)out)[idx];
    float r[4] = {v.x, v.y, v.z, v.w};
    #pragma unroll
    for (int j = 0; j < 4; j++) {
        int c = c0 + j;
        float mean = sums[c] * invN;
        float var = sumsq[c] * invN - mean * mean;
        float scale = rsqrtf(var + BN_EPS) * gamma[c];
        float o = (r[j] - mean) * scale + beta[c];
        r[j] = fmaxf(o, 0.0f);
    }
    ((float4*)out)[idx] = make_float4(r[0], r[1], r[2], r[3]);
}

extern "C" void kernel_launch(void* const* d_in, const int* in_sizes, int n_in,
                              void* d_out, int out_size, void* d_ws, size_t ws_size,
                              hipStream_t stream) {
    const float* x     = (const float*)d_in[0];
    const int*   ei    = (const int*)d_in[1];     // [2][E] (harness delivers int32)
    const float* W     = (const float*)d_in[2];
    // d_in[3] = b : cancels exactly under training-mode BatchNorm -> unused
    const float* gamma = (const float*)d_in[4];
    const float* beta  = (const float*)d_in[5];
    float* out = (float*)d_out;

    const int n = N_NODES, E = N_EDGES;

    // workspace layout
    unsigned short* hb = (unsigned short*)d_ws;     // 12.8M bf16 (25.6 MB)
    float* dinv   = (float*)(hb + 12800000);        // 100k
    int*   deg    = (int*)(dinv + 100000);          // 100k
    int*   offs   = deg + 100000;
    int*   cursor = offs + 100000;
    int*   csr    = cursor + 100000;                // 1.6M
    int*   parts  = csr + 1600000;                  // 512
    int*   pscan  = parts + 512;                    // 512
    float* sums   = (float*)(pscan + 512);          // 128
    float* sumsq  = sums + 128;                     // 128
    unsigned short* Wb = (unsigned short*)(sumsq + 128);  // 16384 bf16

    const int nb256 = (n + 255) / 256;              // 391

    hipMemsetAsync(deg, 0, n * sizeof(int), stream);
    hipMemsetAsync(sums, 0, 256 * sizeof(float), stream);

    k_deg<<<(E + 255) / 256, 256, 0, stream>>>(ei + E, deg, E);
    k_dinv<<<nb256, 256, 0, stream>>>(deg, dinv, n);
    k_part<<<nb256, 256, 0, stream>>>(deg, parts, n);
    k_top<<<1, 256, 0, stream>>>(parts, pscan, nb256);
    k_apply<<<nb256, 256, 0, stream>>>(deg, pscan, offs, cursor, n);
    k_scatter<<<(E + 255) / 256, 256, 0, stream>>>(ei, cursor, csr, E);
    k_wcvt<<<64, 256, 0, stream>>>(W, Wb);

    k_gemm<<<(n + 255) / 256, 256, 0, stream>>>(x, Wb, hb, n);

    k_agg<<<(n + 3) / 4, 256, 0, stream>>>((const unsigned int*)hb, dinv, offs, deg, csr, out, n);

    k_stats<<<512, 256, 0, stream>>>(out, sums, sumsq, n);
    k_bn<<<(n * 32 + 255) / 256, 256, 0, stream>>>(out, sums, sumsq, gamma, beta, n);
}